// Round 9
// baseline (1397.089 us; speedup 1.0000x reference)
//
#include <hip/hip_runtime.h>
#include <stdint.h>

typedef unsigned short ushort_t;
typedef __attribute__((ext_vector_type(8))) __bf16 bf16x8;
typedef __attribute__((ext_vector_type(4))) float f32x4;

#define B_SZ 16384
#define SEQ 50
#define RAWF 109
#define EMB 20
#define DFEAT 128
#define H 512
#define H4 2048
#define NBLK 10
#define OUTD 20

__device__ __forceinline__ ushort_t f2bf(float f) {
    union { float f; uint32_t u; } v; v.f = f;
    uint32_t r = (v.u + 0x7fffu + ((v.u >> 16) & 1u)) >> 16;
    return (ushort_t)r;
}

__device__ __forceinline__ void glds16(const ushort_t* src, ushort_t* dst) {
    __builtin_amdgcn_global_load_lds(
        (const __attribute__((address_space(1))) void*)src,
        (__attribute__((address_space(3))) void*)dst, 16, 0, 0);
}

// ---------------- weight transpose + bf16 convert (vectorized) ----------------
__global__ __launch_bounds__(256)
void transpose_bf16_kernel(const float* __restrict__ src, ushort_t* __restrict__ dst,
                           int K, int N) {
    __shared__ float tile[64][65];
    const int i = blockIdx.z;
    const float* s = src + (size_t)i * K * N;
    ushort_t* d = dst + (size_t)i * K * N;
    const int t = threadIdx.x;
    const int rr = t >> 4;
    const int cc = t & 15;
    const int k0 = blockIdx.y * 64, n0 = blockIdx.x * 64;
#pragma unroll
    for (int r = 0; r < 4; ++r) {
        const int kr = rr + r * 16;
        const float4 v = *(const float4*)(s + (size_t)(k0 + kr) * N + n0 + cc * 4);
        tile[kr][cc * 4 + 0] = v.x;
        tile[kr][cc * 4 + 1] = v.y;
        tile[kr][cc * 4 + 2] = v.z;
        tile[kr][cc * 4 + 3] = v.w;
    }
    __syncthreads();
#pragma unroll
    for (int r = 0; r < 4; ++r) {
        const int nr = rr + r * 16;
        ushort4 o;
        o.x = f2bf(tile[cc * 4 + 0][nr]);
        o.y = f2bf(tile[cc * 4 + 1][nr]);
        o.z = f2bf(tile[cc * 4 + 2][nr]);
        o.w = f2bf(tile[cc * 4 + 3][nr]);
        *(ushort4*)(d + (size_t)(n0 + nr) * K + k0 + cc * 4) = o;
    }
}

// ---------------- seq-len kernel ----------------
__global__ __launch_bounds__(256)
void len_kernel(const int* __restrict__ mask, int* __restrict__ len) {
    const int wid = (blockIdx.x * 256 + threadIdx.x) >> 6;
    const int lane = threadIdx.x & 63;
    if (wid >= B_SZ) return;
    int c = (lane < SEQ) ? mask[(size_t)wid * SEQ + lane] : 0;
#pragma unroll
    for (int off = 32; off > 0; off >>= 1) c += __shfl_down(c, off);
    c = __shfl(c, 0);
    if (lane == 0) len[wid] = c;
}

// ---------------- raw-feature kernel ----------------
__global__ __launch_bounds__(128)
void rawfeat_kernel(const float* __restrict__ inp, const int* __restrict__ len,
                    float* __restrict__ hf, ushort_t* __restrict__ hb,
                    int* __restrict__ ids) {
    const int b = blockIdx.x;
    const int jj = threadIdx.x;
    const float* src = inp + (size_t)b * SEQ * RAWF;
    const int L = len[b];
    const bool active = jj < RAWF;
    float sum = 0.f, mx = -3.0e38f, mn = 3.0e38f, nxt = 0.f;
#pragma unroll 10
    for (int s = 0; s < SEQ; ++s) {
        float v = active ? src[s * RAWF + jj] : 0.f;
        if (s < L) { sum += v; mx = fmaxf(mx, v); mn = fminf(mn, v); }
        if (s == SEQ - 1) nxt = v;
        if (jj == 0) ids[(size_t)b * SEQ + s] = (int)v;
    }
    if (jj >= 1 && jj < RAWF) {
        const int j = 19 + jj;
        const float avg = sum / (float)L;
        mx = fminf(fmaxf(mx, 1e-9f), 1e9f);
        mn = fminf(fmaxf(mn, 1e-9f), 1e9f);
        const size_t base = (size_t)b * H;
        hf[base + j] = avg;             hb[base + j] = f2bf(avg);
        hf[base + DFEAT + j] = mx;      hb[base + DFEAT + j] = f2bf(mx);
        hf[base + 2 * DFEAT + j] = mn;  hb[base + 2 * DFEAT + j] = f2bf(mn);
        hf[base + 3 * DFEAT + j] = nxt; hb[base + 3 * DFEAT + j] = f2bf(nxt);
    }
}

// ---------------- embed-feature kernel ----------------
__global__ __launch_bounds__(256)
void embfeat_kernel(const int* __restrict__ ids, const int* __restrict__ len,
                    const float* __restrict__ embed,
                    float* __restrict__ hf, ushort_t* __restrict__ hb) {
    const int x = threadIdx.x & 31;
    const int row = (blockIdx.x * 256 + threadIdx.x) >> 5;
    if (row >= B_SZ) return;
    const int L = len[row];
    const int* idrow = ids + (size_t)row * SEQ;
    const bool act = x < EMB;
    float sum = 0.f, mx = -3.0e38f, mn = 3.0e38f, nxt = 0.f;
#pragma unroll 10
    for (int s = 0; s < SEQ; ++s) {
        const int id = idrow[s];
        const float v = act ? embed[(size_t)id * EMB + x] : 0.f;
        if (s < L) { sum += v; mx = fmaxf(mx, v); mn = fminf(mn, v); }
        if (s == SEQ - 1) nxt = v;
    }
    if (act) {
        const float avg = sum / (float)L;
        mx = fminf(fmaxf(mx, 1e-9f), 1e9f);
        mn = fminf(fmaxf(mn, 1e-9f), 1e9f);
        const size_t base = (size_t)row * H;
        hf[base + x] = avg;             hb[base + x] = f2bf(avg);
        hf[base + DFEAT + x] = mx;      hb[base + DFEAT + x] = f2bf(mx);
        hf[base + 2 * DFEAT + x] = mn;  hb[base + 2 * DFEAT + x] = f2bf(mn);
        hf[base + 3 * DFEAT + x] = nxt; hb[base + 3 * DFEAT + x] = f2bf(nxt);
    }
}

// ---------------- GEMM1: 256x256 8-phase, race-free stage rotation ----------
// C = relu(A(MxK) * Bt(NxK)^T + bias), bf16 out. 512 thr = 8 waves (2M x 4N).
// LDS 128KB: 2 dbuf x [A 256x64 | B 256x64]; K-tile t in buf t&1.
// Stage rotation (region freed >= one phase before its stage):
//   P0: read A-h0(t),B-h0(t); stage B-h1(t+1) -> OTHER buf (freed 2 groups ago)
//   P1: read B-h1(t);         stage A-h0(t+2) -> freed at P0 end-barrier
//   P2: read A-h1(t);         stage B-h0(t+2) -> freed at P0
//   P3: (no reads)            stage A-h1(t+2) -> freed at P2; vmcnt(6); barrier
// vmcnt(6) ledger: last load needed by group t+1 is B-h1(t+1) staged at P0;
// loads after it = P1,P2,P3 stages = 6 -> counted wait, never 0 in steady state.
__global__ __launch_bounds__(512, 2)
void gemm1_8phase(const ushort_t* __restrict__ A, const ushort_t* __restrict__ Bt,
                  const float* __restrict__ bias, ushort_t* __restrict__ outBf,
                  int M, int N, int K) {
    __shared__ alignas(16) ushort_t lAb[2][256 * 64];
    __shared__ alignas(16) ushort_t lBb[2][256 * 64];
    const int tid = threadIdx.x;
    const int lane = tid & 63;
    const int w = tid >> 6;          // 0..7
    const int wm = w >> 2;           // 0..1 (128-row band)
    const int wn = w & 3;            // 0..3 (64-col band)
    const int frow = lane & 15;
    const int k16 = lane >> 4;

    // XCD-aware bijective swizzle (nwg = 512, %8 == 0)
    const int gx = N >> 8;
    const int nwg = (M >> 8) * gx;
    const int cpx = nwg >> 3;
    const int bid = blockIdx.x;
    const int wg = (bid & 7) * cpx + (bid >> 3);
    const int ntile = wg % gx, mtile = wg / gx;

    const ushort_t* Abase = A + (size_t)mtile * 256 * K;
    const ushort_t* Bbase = Bt + (size_t)ntile * 256 * K;

    // staging geometry: per half-panel (128 rows x 64 cols), wave w covers
    // half-rows [w*16, w*16+16), 2 loads of 8 rows; source col pre-swizzled.
    const int l3 = lane >> 3;
    const int csrc = (lane & 7) ^ l3;
    const int hr0 = w * 16 + l3, hr1 = hr0 + 8;
    const ushort_t* pA00 = Abase + (size_t)(((hr0 >> 6) << 7) + (hr0 & 63)) * K + csrc * 8;
    const ushort_t* pA01 = Abase + (size_t)(((hr1 >> 6) << 7) + (hr1 & 63)) * K + csrc * 8;
    const ushort_t* pA10 = Abase + (size_t)(((hr0 >> 6) << 7) + 64 + (hr0 & 63)) * K + csrc * 8;
    const ushort_t* pA11 = Abase + (size_t)(((hr1 >> 6) << 7) + 64 + (hr1 & 63)) * K + csrc * 8;
    const ushort_t* pB00 = Bbase + (size_t)(((hr0 >> 5) << 6) + (hr0 & 31)) * K + csrc * 8;
    const ushort_t* pB01 = Bbase + (size_t)(((hr1 >> 5) << 6) + (hr1 & 31)) * K + csrc * 8;
    const ushort_t* pB10 = Bbase + (size_t)(((hr0 >> 5) << 6) + 32 + (hr0 & 31)) * K + csrc * 8;
    const ushort_t* pB11 = Bbase + (size_t)(((hr1 >> 5) << 6) + 32 + (hr1 & 31)) * K + csrc * 8;
    const int d0 = (w * 16) * 64, d1 = (w * 16 + 8) * 64;   // LDS dest (+half*8192)

    f32x4 acc00[4][2], acc01[4][2], acc10[4][2], acc11[4][2];
#pragma unroll
    for (int mf = 0; mf < 4; ++mf)
#pragma unroll
        for (int nf = 0; nf < 2; ++nf) {
            acc00[mf][nf] = (f32x4)(0.f); acc01[mf][nf] = (f32x4)(0.f);
            acc10[mf][nf] = (f32x4)(0.f); acc11[mf][nf] = (f32x4)(0.f);
        }

    auto stage2 = [&](ushort_t* base, int halfofs, const ushort_t* s0,
                      const ushort_t* s1, int kt) {
        const size_t ko = (size_t)kt * 64;
        glds16(s0 + ko, base + halfofs + d0);
        glds16(s1 + ko, base + halfofs + d1);
    };
    auto readA = [&](const ushort_t* la, int mh, bf16x8 (&af)[4][2]) {
#pragma unroll
        for (int mf = 0; mf < 4; ++mf)
#pragma unroll
            for (int ks = 0; ks < 2; ++ks) {
                const int row = mh * 128 + wm * 64 + mf * 16 + frow;
                const int c = (ks * 4 + k16) ^ (frow & 7);
                af[mf][ks] = *(const bf16x8*)(la + row * 64 + c * 8);
            }
    };
    auto readB = [&](const ushort_t* lb, int nh, bf16x8 (&bq)[2][2]) {
#pragma unroll
        for (int nf = 0; nf < 2; ++nf)
#pragma unroll
            for (int ks = 0; ks < 2; ++ks) {
                const int row = nh * 128 + wn * 32 + nf * 16 + frow;
                const int c = (ks * 4 + k16) ^ (frow & 7);
                bq[nf][ks] = *(const bf16x8*)(lb + row * 64 + c * 8);
            }
    };
    auto mfmaQ = [&](bf16x8 (&af)[4][2], bf16x8 (&bq)[2][2], f32x4 (&ac)[4][2]) {
        __builtin_amdgcn_s_setprio(1);
#pragma unroll
        for (int mf = 0; mf < 4; ++mf)
#pragma unroll
            for (int nf = 0; nf < 2; ++nf)
#pragma unroll
                for (int ks = 0; ks < 2; ++ks)
                    ac[mf][nf] = __builtin_amdgcn_mfma_f32_16x16x32_bf16(
                        af[mf][ks], bq[nf][ks], ac[mf][nf], 0, 0, 0);
        __builtin_amdgcn_s_setprio(0);
    };

    const int nkt = K >> 6;
    bf16x8 af[4][2], b0q[2][2], b1q[2][2];

    // prologue: tile0 fully + tile1 minus B-h1 (14 loads); vmcnt(6) -> tile0 in
    stage2(lAb[0], 0,    pA00, pA01, 0);
    stage2(lBb[0], 0,    pB00, pB01, 0);
    stage2(lAb[0], 8192, pA10, pA11, 0);
    stage2(lBb[0], 8192, pB10, pB11, 0);
    stage2(lAb[1], 0,    pA00, pA01, 1);
    stage2(lBb[1], 0,    pB00, pB01, 1);
    stage2(lAb[1], 8192, pA10, pA11, 1);
    asm volatile("s_waitcnt vmcnt(6)" ::: "memory");
    __builtin_amdgcn_s_barrier();

    for (int t = 0; t < nkt; ++t) {
        ushort_t* la = lAb[t & 1];
        ushort_t* lb = lBb[t & 1];
        ushort_t* lbN = lBb[(t + 1) & 1];
        const bool s1 = (t + 1) < nkt;
        const bool s2 = (t + 2) < nkt;
        // P0: quadrant (0,0); stage B-h1(t+1) into other buffer
        readA(la, 0, af);
        readB(lb, 0, b0q);
        if (s1) stage2(lbN, 8192, pB10, pB11, t + 1);
        __builtin_amdgcn_s_barrier();
        asm volatile("s_waitcnt lgkmcnt(0)" ::: "memory");
        __builtin_amdgcn_sched_barrier(0);
        mfmaQ(af, b0q, acc00);
        __builtin_amdgcn_s_barrier();
        // P1: quadrant (0,1); stage A-h0(t+2) (region freed at P0 end barrier)
        readB(lb, 1, b1q);
        if (s2) stage2(la, 0, pA00, pA01, t + 2);
        __builtin_amdgcn_s_barrier();
        asm volatile("s_waitcnt lgkmcnt(0)" ::: "memory");
        __builtin_amdgcn_sched_barrier(0);
        mfmaQ(af, b1q, acc01);
        __builtin_amdgcn_s_barrier();
        // P2: quadrant (1,0); stage B-h0(t+2) (freed at P0)
        readA(la, 1, af);
        if (s2) stage2(lb, 0, pB00, pB01, t + 2);
        __builtin_amdgcn_s_barrier();
        asm volatile("s_waitcnt lgkmcnt(0)" ::: "memory");
        __builtin_amdgcn_sched_barrier(0);
        mfmaQ(af, b0q, acc10);
        __builtin_amdgcn_s_barrier();
        // P3: quadrant (1,1); stage A-h1(t+2) (freed at P2); counted vmcnt
        if (s2) {
            stage2(la, 8192, pA10, pA11, t + 2);
            asm volatile("s_waitcnt vmcnt(6)" ::: "memory");
        } else {
            asm volatile("s_waitcnt vmcnt(0)" ::: "memory");
        }
        __builtin_amdgcn_s_barrier();
        __builtin_amdgcn_sched_barrier(0);
        mfmaQ(af, b1q, acc11);
        __builtin_amdgcn_s_barrier();
    }

    // epilogue
    auto epi = [&](f32x4 (&ac)[4][2], int mh, int nh) {
#pragma unroll
        for (int mf = 0; mf < 4; ++mf)
#pragma unroll
            for (int nf = 0; nf < 2; ++nf) {
                const int row0 = mtile * 256 + wm * 128 + mh * 64 + mf * 16 + (lane >> 4) * 4;
                const int col = ntile * 256 + wn * 64 + nh * 32 + nf * 16 + (lane & 15);
                const float bc = bias[col];
#pragma unroll
                for (int jj = 0; jj < 4; ++jj) {
                    float v = ac[mf][nf][jj] + bc;
                    v = v > 0.f ? v : 0.f;
                    outBf[(size_t)(row0 + jj) * N + col] = f2bf(v);
                }
            }
    };
    epi(acc00, 0, 0); epi(acc01, 0, 1); epi(acc10, 1, 0); epi(acc11, 1, 1);
}

// ---------------- GEMM2: 128x128 m97-class (proven) ----------------
__global__ __launch_bounds__(256, 3)
void gemm2_kernel(const ushort_t* __restrict__ A, const ushort_t* __restrict__ Bt,
                  const float* __restrict__ bias,
                  float* __restrict__ hf, ushort_t* __restrict__ hb,
                  int M, int N, int K) {
    __shared__ alignas(16) ushort_t lA[128 * 64];
    __shared__ alignas(16) ushort_t lB[128 * 64];
    const int tid = threadIdx.x;
    const int lane = tid & 63;
    const int w = tid >> 6;
    const int wm = w >> 1, wn = w & 1;

    const int gx = N >> 7;
    const int nwg = (M >> 7) * gx;
    const int cpx = nwg >> 3;
    const int bid = blockIdx.x;
    const int wg = (bid & 7) * cpx + (bid >> 3);
    const int ntile = wg % gx, mtile = wg / gx;

    const ushort_t* Abase = A + (size_t)mtile * 128 * K;
    const ushort_t* Bbase = Bt + (size_t)ntile * 128 * K;

    f32x4 acc[4][4];
#pragma unroll
    for (int a = 0; a < 4; ++a)
#pragma unroll
        for (int b = 0; b < 4; ++b) acc[a][b] = (f32x4)(0.f);

    const int l3 = lane >> 3;
    const int cl = (lane & 7) ^ l3;
    const int frow = lane & 15;
    const int k16b = lane >> 4;

    const int nkt = K >> 6;
    for (int kt = 0; kt < nkt; ++kt) {
#pragma unroll
        for (int it = 0; it < 4; ++it) {
            const int row = w * 32 + it * 8 + l3;
            const ushort_t* ga = Abase + (size_t)row * K + kt * 64 + cl * 8;
            const ushort_t* gb = Bbase + (size_t)row * K + kt * 64 + cl * 8;
            glds16(ga, lA + (w * 32 + it * 8) * 64);
            glds16(gb, lB + (w * 32 + it * 8) * 64);
        }
        asm volatile("s_waitcnt vmcnt(0)" ::: "memory");
        __syncthreads();

        bf16x8 af[4][2], bfg[4][2];
#pragma unroll
        for (int mf = 0; mf < 4; ++mf)
#pragma unroll
            for (int ks = 0; ks < 2; ++ks) {
                const int row = wm * 64 + mf * 16 + frow;
                const int c = (ks * 4 + k16b) ^ (row & 7);
                af[mf][ks] = *(const bf16x8*)(lA + row * 64 + c * 8);
            }
#pragma unroll
        for (int nf = 0; nf < 4; ++nf)
#pragma unroll
            for (int ks = 0; ks < 2; ++ks) {
                const int row = wn * 64 + nf * 16 + frow;
                const int c = (ks * 4 + k16b) ^ (row & 7);
                bfg[nf][ks] = *(const bf16x8*)(lB + row * 64 + c * 8);
            }
#pragma unroll
        for (int mf = 0; mf < 4; ++mf)
#pragma unroll
            for (int nf = 0; nf < 4; ++nf)
#pragma unroll
                for (int ks = 0; ks < 2; ++ks)
                    acc[mf][nf] = __builtin_amdgcn_mfma_f32_16x16x32_bf16(
                        af[mf][ks], bfg[nf][ks], acc[mf][nf], 0, 0, 0);
        __syncthreads();
    }

#pragma unroll
    for (int mf = 0; mf < 4; ++mf)
#pragma unroll
        for (int nf = 0; nf < 4; ++nf) {
            const int row0 = mtile * 128 + wm * 64 + mf * 16 + (lane >> 4) * 4;
            const int col = ntile * 128 + wn * 64 + nf * 16 + (lane & 15);
            const float bcol = bias[col];
#pragma unroll
            for (int jj = 0; jj < 4; ++jj) {
                float v = acc[mf][nf][jj] + bcol;
                v = v > 0.f ? v : 0.f;
                const size_t idx = (size_t)(row0 + jj) * N + col;
                float nh = hf[idx] + v;
                hf[idx] = nh;
                hb[idx] = f2bf(nh);
            }
        }
}

// ---------------- final head ----------------
__global__ __launch_bounds__(256)
void final_kernel(const float* __restrict__ hf, const float* __restrict__ Wf,
                  const float* __restrict__ bfv, float* __restrict__ out) {
    const int gid = blockIdx.x * 256 + threadIdx.x;
    if (gid >= B_SZ * OUTD) return;
    const int b = gid / OUTD, o = gid % OUTD;
    const float* hrow = hf + (size_t)b * H;
    float acc = bfv[o];
    for (int k = 0; k < H; ++k) acc += hrow[k] * Wf[k * OUTD + o];
    out[gid] = acc;
}

extern "C" void kernel_launch(void* const* d_in, const int* in_sizes, int n_in,
                              void* d_out, int out_size, void* d_ws, size_t ws_size,
                              hipStream_t stream) {
    const float* inp   = (const float*)d_in[0];
    const int*   mask  = (const int*)d_in[1];
    const float* embed = (const float*)d_in[2];
    const float* W1    = (const float*)d_in[3];
    const float* b1    = (const float*)d_in[4];
    const float* W2    = (const float*)d_in[5];
    const float* b2    = (const float*)d_in[6];
    const float* Wf    = (const float*)d_in[7];
    const float* bfv   = (const float*)d_in[8];
    float* out = (float*)d_out;

    char* ws = (char*)d_ws;
    ushort_t* W1t = (ushort_t*)ws;
    ushort_t* W2t = W1t + (size_t)NBLK * H4 * H;
    float*    hf  = (float*)(W2t + (size_t)NBLK * H * H4);
    ushort_t* hb  = (ushort_t*)(hf + (size_t)B_SZ * H);
    ushort_t* T   = hb + (size_t)B_SZ * H;
    int* ids = (int*)T;
    int* lenb = ids + (size_t)B_SZ * SEQ;

    transpose_bf16_kernel<<<dim3(H4 / 64, H / 64, NBLK), 256, 0, stream>>>(W1, W1t, H, H4);
    transpose_bf16_kernel<<<dim3(H / 64, H4 / 64, NBLK), 256, 0, stream>>>(W2, W2t, H4, H);

    len_kernel<<<(B_SZ * 64 + 255) / 256, 256, 0, stream>>>(mask, lenb);
    rawfeat_kernel<<<B_SZ, 128, 0, stream>>>(inp, lenb, hf, hb, ids);
    embfeat_kernel<<<(B_SZ * 32 + 255) / 256, 256, 0, stream>>>(ids, lenb, embed, hf, hb);

    for (int i = 0; i < NBLK; ++i) {
        gemm1_8phase<<<(B_SZ / 256) * (H4 / 256), 512, 0, stream>>>(
            hb, W1t + (size_t)i * H4 * H, b1 + (size_t)i * H4, T, B_SZ, H4, H);
        gemm2_kernel<<<(B_SZ / 128) * (H / 128), 256, 0, stream>>>(
            T, W2t + (size_t)i * H * H4, b2 + (size_t)i * H, hf, hb,
            B_SZ, H, H4);
    }

    final_kernel<<<(B_SZ * OUTD + 255) / 256, 256, 0, stream>>>(hf, Wf, bfv, out);
}

// Round 10
// 1245.422 us; speedup vs baseline: 1.1218x; 1.1218x over previous
//
#include <hip/hip_runtime.h>
#include <stdint.h>

typedef unsigned short ushort_t;
typedef __attribute__((ext_vector_type(8))) __bf16 bf16x8;
typedef __attribute__((ext_vector_type(4))) float f32x4;
typedef float f32x4u __attribute__((ext_vector_type(4), aligned(4)));

#define B_SZ 16384
#define SEQ 50
#define RAWF 109
#define EMB 20
#define DFEAT 128
#define H 512
#define H4 2048
#define NBLK 10
#define OUTD 20

__device__ __forceinline__ ushort_t f2bf(float f) {
    union { float f; uint32_t u; } v; v.f = f;
    uint32_t r = (v.u + 0x7fffu + ((v.u >> 16) & 1u)) >> 16;
    return (ushort_t)r;
}

__device__ __forceinline__ void glds16(const ushort_t* src, ushort_t* dst) {
    __builtin_amdgcn_global_load_lds(
        (const __attribute__((address_space(1))) void*)src,
        (__attribute__((address_space(3))) void*)dst, 16, 0, 0);
}

// ---------------- weight transpose + bf16 convert (vectorized) ----------------
__global__ __launch_bounds__(256)
void transpose_bf16_kernel(const float* __restrict__ src, ushort_t* __restrict__ dst,
                           int K, int N) {
    __shared__ float tile[64][65];
    const int i = blockIdx.z;
    const float* s = src + (size_t)i * K * N;
    ushort_t* d = dst + (size_t)i * K * N;
    const int t = threadIdx.x;
    const int rr = t >> 4;
    const int cc = t & 15;
    const int k0 = blockIdx.y * 64, n0 = blockIdx.x * 64;
#pragma unroll
    for (int r = 0; r < 4; ++r) {
        const int kr = rr + r * 16;
        const float4 v = *(const float4*)(s + (size_t)(k0 + kr) * N + n0 + cc * 4);
        tile[kr][cc * 4 + 0] = v.x;
        tile[kr][cc * 4 + 1] = v.y;
        tile[kr][cc * 4 + 2] = v.z;
        tile[kr][cc * 4 + 3] = v.w;
    }
    __syncthreads();
#pragma unroll
    for (int r = 0; r < 4; ++r) {
        const int nr = rr + r * 16;
        ushort4 o;
        o.x = f2bf(tile[cc * 4 + 0][nr]);
        o.y = f2bf(tile[cc * 4 + 1][nr]);
        o.z = f2bf(tile[cc * 4 + 2][nr]);
        o.w = f2bf(tile[cc * 4 + 3][nr]);
        *(ushort4*)(d + (size_t)(n0 + nr) * K + k0 + cc * 4) = o;
    }
}

// ---------------- seq-len kernel ----------------
__global__ __launch_bounds__(256)
void len_kernel(const int* __restrict__ mask, int* __restrict__ len) {
    const int wid = (blockIdx.x * 256 + threadIdx.x) >> 6;
    const int lane = threadIdx.x & 63;
    if (wid >= B_SZ) return;
    int c = (lane < SEQ) ? mask[(size_t)wid * SEQ + lane] : 0;
#pragma unroll
    for (int off = 32; off > 0; off >>= 1) c += __shfl_down(c, off);
    c = __shfl(c, 0);
    if (lane == 0) len[wid] = c;
}

// ---------------- raw-feature kernel v2: float4 over feature axis ----------
// 32 lanes per row, 8 rows per 256-thread block. Thread q in [0,27] owns
// input cols 4q..4q+3 via one (4B-aligned) float4 load per s; col 0 = ids
// (extracted by q==0), cols 1..108 -> h feature j = 19+c.
__global__ __launch_bounds__(256)
void rawfeat_kernel(const float* __restrict__ inp, const int* __restrict__ len,
                    float* __restrict__ hf, ushort_t* __restrict__ hb,
                    int* __restrict__ ids) {
    const int g = threadIdx.x >> 5;
    const int q = threadIdx.x & 31;
    const int b = blockIdx.x * 8 + g;
    const float* src = inp + (size_t)b * SEQ * RAWF;
    const int L = len[b];
    const int c0 = q * 4;
    f32x4u sum = (f32x4u)(0.f);
    f32x4u mx = (f32x4u)(-3.0e38f);
    f32x4u mn = (f32x4u)(3.0e38f);
    f32x4u nxt = (f32x4u)(0.f);
#pragma unroll 5
    for (int s = 0; s < SEQ; ++s) {
        f32x4u v = (f32x4u)(0.f);
        if (q < 27) {
            v = *(const f32x4u*)(src + s * RAWF + c0);
        } else if (q == 27) {
            v.x = src[s * RAWF + 108];
        }
        if (q == 0) ids[(size_t)b * SEQ + s] = (int)v.x;
        if (s < L) {
            sum += v;
            mx.x = fmaxf(mx.x, v.x); mx.y = fmaxf(mx.y, v.y);
            mx.z = fmaxf(mx.z, v.z); mx.w = fmaxf(mx.w, v.w);
            mn.x = fminf(mn.x, v.x); mn.y = fminf(mn.y, v.y);
            mn.z = fminf(mn.z, v.z); mn.w = fminf(mn.w, v.w);
        }
        if (s == SEQ - 1) nxt = v;
    }
    if (q < 28) {
        const float rinv = 1.0f / (float)L;
        const size_t base = (size_t)b * H;
#pragma unroll
        for (int e = 0; e < 4; ++e) {
            const int c = c0 + e;
            if (c < 1 || c > 108) continue;
            const int j = 19 + c;
            const float a = sum[e] * rinv;
            const float mxe = fminf(fmaxf(mx[e], 1e-9f), 1e9f);
            const float mne = fminf(fmaxf(mn[e], 1e-9f), 1e9f);
            const float nx = nxt[e];
            hf[base + j] = a;               hb[base + j] = f2bf(a);
            hf[base + DFEAT + j] = mxe;     hb[base + DFEAT + j] = f2bf(mxe);
            hf[base + 2 * DFEAT + j] = mne; hb[base + 2 * DFEAT + j] = f2bf(mne);
            hf[base + 3 * DFEAT + j] = nx;  hb[base + 3 * DFEAT + j] = f2bf(nx);
        }
    }
}

// ---------------- embed-feature kernel ----------------
__global__ __launch_bounds__(256)
void embfeat_kernel(const int* __restrict__ ids, const int* __restrict__ len,
                    const float* __restrict__ embed,
                    float* __restrict__ hf, ushort_t* __restrict__ hb) {
    const int x = threadIdx.x & 31;
    const int row = (blockIdx.x * 256 + threadIdx.x) >> 5;
    if (row >= B_SZ) return;
    const int L = len[row];
    const int* idrow = ids + (size_t)row * SEQ;
    const bool act = x < EMB;
    float sum = 0.f, mx = -3.0e38f, mn = 3.0e38f, nxt = 0.f;
#pragma unroll 10
    for (int s = 0; s < SEQ; ++s) {
        const int id = idrow[s];
        const float v = act ? embed[(size_t)id * EMB + x] : 0.f;
        if (s < L) { sum += v; mx = fmaxf(mx, v); mn = fminf(mn, v); }
        if (s == SEQ - 1) nxt = v;
    }
    if (act) {
        const float avg = sum / (float)L;
        mx = fminf(fmaxf(mx, 1e-9f), 1e9f);
        mn = fminf(fmaxf(mn, 1e-9f), 1e9f);
        const size_t base = (size_t)row * H;
        hf[base + x] = avg;             hb[base + x] = f2bf(avg);
        hf[base + DFEAT + x] = mx;      hb[base + DFEAT + x] = f2bf(mx);
        hf[base + 2 * DFEAT + x] = mn;  hb[base + 2 * DFEAT + x] = f2bf(mn);
        hf[base + 3 * DFEAT + x] = nxt; hb[base + 3 * DFEAT + x] = f2bf(nxt);
    }
}

// ---------------- GEMM: C = relu(A(MxK) * Bt(NxK)^T + bias) ----------------
// 128x128 tile, BK=64, 4 waves, single-buffered m97-class structure.
// MODE 0: write bf16 out. MODE 1: hf += relu(...); hb = bf16(hf)
template <int MODE>
__global__ __launch_bounds__(256, 3)
void gemm_kernel(const ushort_t* __restrict__ A, const ushort_t* __restrict__ Bt,
                 const float* __restrict__ bias,
                 ushort_t* __restrict__ outBf,
                 float* __restrict__ hf, ushort_t* __restrict__ hb,
                 int M, int N, int K) {
    __shared__ alignas(16) ushort_t lA[128 * 64];
    __shared__ alignas(16) ushort_t lB[128 * 64];
    const int tid = threadIdx.x;
    const int lane = tid & 63;
    const int w = tid >> 6;
    const int wm = w >> 1, wn = w & 1;

    const int gx = N >> 7;
    const int nwg = (M >> 7) * gx;
    const int cpx = nwg >> 3;
    const int bid = blockIdx.x;
    const int wg = (bid & 7) * cpx + (bid >> 3);
    const int ntile = wg % gx, mtile = wg / gx;

    const ushort_t* Abase = A + (size_t)mtile * 128 * K;
    const ushort_t* Bbase = Bt + (size_t)ntile * 128 * K;

    f32x4 acc[4][4];
#pragma unroll
    for (int a = 0; a < 4; ++a)
#pragma unroll
        for (int b = 0; b < 4; ++b) acc[a][b] = (f32x4)(0.f);

    const int l3 = lane >> 3;
    const int cl = (lane & 7) ^ l3;
    const int frow = lane & 15;
    const int k16b = lane >> 4;

    const int nkt = K >> 6;
    for (int kt = 0; kt < nkt; ++kt) {
#pragma unroll
        for (int it = 0; it < 4; ++it) {
            const int row = w * 32 + it * 8 + l3;
            const ushort_t* ga = Abase + (size_t)row * K + kt * 64 + cl * 8;
            const ushort_t* gb = Bbase + (size_t)row * K + kt * 64 + cl * 8;
            glds16(ga, lA + (w * 32 + it * 8) * 64);
            glds16(gb, lB + (w * 32 + it * 8) * 64);
        }
        asm volatile("s_waitcnt vmcnt(0)" ::: "memory");
        __syncthreads();

        bf16x8 af[4][2], bfg[4][2];
#pragma unroll
        for (int mf = 0; mf < 4; ++mf)
#pragma unroll
            for (int ks = 0; ks < 2; ++ks) {
                const int row = wm * 64 + mf * 16 + frow;
                const int c = (ks * 4 + k16b) ^ (row & 7);
                af[mf][ks] = *(const bf16x8*)(lA + row * 64 + c * 8);
            }
#pragma unroll
        for (int nf = 0; nf < 4; ++nf)
#pragma unroll
            for (int ks = 0; ks < 2; ++ks) {
                const int row = wn * 64 + nf * 16 + frow;
                const int c = (ks * 4 + k16b) ^ (row & 7);
                bfg[nf][ks] = *(const bf16x8*)(lB + row * 64 + c * 8);
            }
#pragma unroll
        for (int mf = 0; mf < 4; ++mf)
#pragma unroll
            for (int nf = 0; nf < 4; ++nf)
#pragma unroll
                for (int ks = 0; ks < 2; ++ks)
                    acc[mf][nf] = __builtin_amdgcn_mfma_f32_16x16x32_bf16(
                        af[mf][ks], bfg[nf][ks], acc[mf][nf], 0, 0, 0);
        __syncthreads();
    }

#pragma unroll
    for (int mf = 0; mf < 4; ++mf)
#pragma unroll
        for (int nf = 0; nf < 4; ++nf) {
            const int row0 = mtile * 128 + wm * 64 + mf * 16 + (lane >> 4) * 4;
            const int col = ntile * 128 + wn * 64 + nf * 16 + (lane & 15);
            const float bcol = bias[col];
#pragma unroll
            for (int jj = 0; jj < 4; ++jj) {
                float v = acc[mf][nf][jj] + bcol;
                v = v > 0.f ? v : 0.f;
                const size_t idx = (size_t)(row0 + jj) * N + col;
                if (MODE == 0) {
                    outBf[idx] = f2bf(v);
                } else {
                    float nh = hf[idx] + v;
                    hf[idx] = nh;
                    hb[idx] = f2bf(nh);
                }
            }
        }
}

// ---------------- final head ----------------
__global__ __launch_bounds__(256)
void final_kernel(const float* __restrict__ hf, const float* __restrict__ Wf,
                  const float* __restrict__ bfv, float* __restrict__ out) {
    const int gid = blockIdx.x * 256 + threadIdx.x;
    if (gid >= B_SZ * OUTD) return;
    const int b = gid / OUTD, o = gid % OUTD;
    const float* hrow = hf + (size_t)b * H;
    float acc = bfv[o];
    for (int k = 0; k < H; ++k) acc += hrow[k] * Wf[k * OUTD + o];
    out[gid] = acc;
}

extern "C" void kernel_launch(void* const* d_in, const int* in_sizes, int n_in,
                              void* d_out, int out_size, void* d_ws, size_t ws_size,
                              hipStream_t stream) {
    const float* inp   = (const float*)d_in[0];
    const int*   mask  = (const int*)d_in[1];
    const float* embed = (const float*)d_in[2];
    const float* W1    = (const float*)d_in[3];
    const float* b1    = (const float*)d_in[4];
    const float* W2    = (const float*)d_in[5];
    const float* b2    = (const float*)d_in[6];
    const float* Wf    = (const float*)d_in[7];
    const float* bfv   = (const float*)d_in[8];
    float* out = (float*)d_out;

    char* ws = (char*)d_ws;
    ushort_t* W1t = (ushort_t*)ws;
    ushort_t* W2t = W1t + (size_t)NBLK * H4 * H;
    float*    hf  = (float*)(W2t + (size_t)NBLK * H * H4);
    ushort_t* hb  = (ushort_t*)(hf + (size_t)B_SZ * H);
    ushort_t* T   = hb + (size_t)B_SZ * H;
    int* ids = (int*)T;
    int* lenb = ids + (size_t)B_SZ * SEQ;

    transpose_bf16_kernel<<<dim3(H4 / 64, H / 64, NBLK), 256, 0, stream>>>(W1, W1t, H, H4);
    transpose_bf16_kernel<<<dim3(H / 64, H4 / 64, NBLK), 256, 0, stream>>>(W2, W2t, H4, H);

    len_kernel<<<(B_SZ * 64 + 255) / 256, 256, 0, stream>>>(mask, lenb);
    rawfeat_kernel<<<B_SZ / 8, 256, 0, stream>>>(inp, lenb, hf, hb, ids);
    embfeat_kernel<<<(B_SZ * 32 + 255) / 256, 256, 0, stream>>>(ids, lenb, embed, hf, hb);

    for (int i = 0; i < NBLK; ++i) {
        gemm_kernel<0><<<(B_SZ / 128) * (H4 / 128), 256, 0, stream>>>(
            hb, W1t + (size_t)i * H4 * H, b1 + (size_t)i * H4, T, nullptr, nullptr,
            B_SZ, H4, H);
        gemm_kernel<1><<<(B_SZ / 128) * (H / 128), 256, 0, stream>>>(
            T, W2t + (size_t)i * H * H4, b2 + (size_t)i * H, nullptr, hf, hb,
            B_SZ, H, H4);
    }

    final_kernel<<<(B_SZ * OUTD + 255) / 256, 256, 0, stream>>>(hf, Wf, bfv, out);
}